// Round 3
// baseline (424.926 us; speedup 1.0000x reference)
//
#include <hip/hip_runtime.h>

#define NUM_CLASSES 1000
#define FEAT_DIM    256
#define MOMENTUM    0.9f

// ---------------------------------------------------------------------------
// Kernel 1: per-class histogram with LDS privatization (4 KB, 1000 bins).
// ---------------------------------------------------------------------------
__global__ void __launch_bounds__(256) hist_kernel(
    const int* __restrict__ labels, int lstride, int n, int* __restrict__ counts) {
    __shared__ int h[NUM_CLASSES];
    for (int i = threadIdx.x; i < NUM_CLASSES; i += blockDim.x) h[i] = 0;
    __syncthreads();
    for (int i = blockIdx.x * blockDim.x + threadIdx.x; i < n;
         i += gridDim.x * blockDim.x) {
        int c = labels[(size_t)i * lstride];
        atomicAdd(&h[c], 1);
    }
    __syncthreads();
    for (int i = threadIdx.x; i < NUM_CLASSES; i += blockDim.x) {
        int v = h[i];
        if (v) atomicAdd(&counts[i], v);
    }
}

// ---------------------------------------------------------------------------
// Kernel 2: exclusive prefix-sum of the 1000 counts (single 1024-thread block,
// Hillis-Steele in LDS). Writes both offsets (stable) and cursor (consumed).
// ---------------------------------------------------------------------------
__global__ void __launch_bounds__(1024) scan_kernel(
    const int* __restrict__ counts, int* __restrict__ offsets,
    int* __restrict__ cursor) {
    __shared__ int buf[1024];
    int t = threadIdx.x;
    int v = (t < NUM_CLASSES) ? counts[t] : 0;
    buf[t] = v;
    __syncthreads();
    for (int off = 1; off < 1024; off <<= 1) {
        int x = (t >= off) ? buf[t - off] : 0;
        __syncthreads();
        buf[t] += x;
        __syncthreads();
    }
    if (t < NUM_CLASSES) {
        int excl = buf[t] - v;   // inclusive -> exclusive
        offsets[t] = excl;
        cursor[t]  = excl;
    }
}

// ---------------------------------------------------------------------------
// Kernel 3: scatter row indices into per-class contiguous lists.
// 262K atomics over 1000 cursors — cheap.
// ---------------------------------------------------------------------------
__global__ void __launch_bounds__(256) scatter_kernel(
    const int* __restrict__ labels, int lstride, int n,
    int* __restrict__ cursor, int* __restrict__ idxbuf) {
    for (int i = blockIdx.x * blockDim.x + threadIdx.x; i < n;
         i += gridDim.x * blockDim.x) {
        int c = labels[(size_t)i * lstride];
        int pos = atomicAdd(&cursor[c], 1);
        idxbuf[pos] = i;
    }
}

// ---------------------------------------------------------------------------
// Kernel 4: per-class reduction + EMA epilogue.
// One block per class. 256 threads = 4 groups x 64 lanes. Each group reads a
// full 1 KB feature row as 64 x float4 (16 B/lane, coalesced); groups stride
// over the class's row list (stride 4), unroll x4 => 4 outstanding 16 B
// loads/lane. 4-way cross-group combine in LDS, then EMA + float4 store.
// ---------------------------------------------------------------------------
__global__ void __launch_bounds__(FEAT_DIM) reduce_ema_kernel(
    const float* __restrict__ feat, const float* __restrict__ proto,
    const int* __restrict__ offsets, const int* __restrict__ counts,
    const int* __restrict__ idxbuf, float* __restrict__ out) {
    const int c    = blockIdx.x;
    const int t    = threadIdx.x;
    const int g    = t >> 6;        // group 0..3
    const int lane = t & 63;        // lane within group = float4 slot
    const int start = offsets[c];
    const int cnt   = counts[c];

    float4 a0 = make_float4(0.f, 0.f, 0.f, 0.f);
    float4 a1 = make_float4(0.f, 0.f, 0.f, 0.f);
    float4 a2 = make_float4(0.f, 0.f, 0.f, 0.f);
    float4 a3 = make_float4(0.f, 0.f, 0.f, 0.f);

    int j = g;
    for (; j + 12 < cnt; j += 16) {   // rows j, j+4, j+8, j+12 all valid
        int r0 = idxbuf[start + j];
        int r1 = idxbuf[start + j + 4];
        int r2 = idxbuf[start + j + 8];
        int r3 = idxbuf[start + j + 12];
        float4 f0 = *(reinterpret_cast<const float4*>(feat + (size_t)r0 * FEAT_DIM) + lane);
        float4 f1 = *(reinterpret_cast<const float4*>(feat + (size_t)r1 * FEAT_DIM) + lane);
        float4 f2 = *(reinterpret_cast<const float4*>(feat + (size_t)r2 * FEAT_DIM) + lane);
        float4 f3 = *(reinterpret_cast<const float4*>(feat + (size_t)r3 * FEAT_DIM) + lane);
        a0.x += f0.x; a0.y += f0.y; a0.z += f0.z; a0.w += f0.w;
        a1.x += f1.x; a1.y += f1.y; a1.z += f1.z; a1.w += f1.w;
        a2.x += f2.x; a2.y += f2.y; a2.z += f2.z; a2.w += f2.w;
        a3.x += f3.x; a3.y += f3.y; a3.z += f3.w == f3.w ? f3.w * 0.f : 0.f; // placeholder avoided below
        a3.x -= 0.f; // (no-op)
        a3.x += 0.f;
        a3.x += 0.f;
        // correct accumulation for f3 (kept explicit):
        a3.y += f3.y; a3.z += f3.z; a3.w += f3.w;
        a3.x += f3.x;
    }
    for (; j < cnt; j += 4) {         // tail: one row at a time per group
        int r0 = idxbuf[start + j];
        float4 f0 = *(reinterpret_cast<const float4*>(feat + (size_t)r0 * FEAT_DIM) + lane);
        a0.x += f0.x; a0.y += f0.y; a0.z += f0.z; a0.w += f0.w;
    }
    a0.x += a1.x; a0.y += a1.y; a0.z += a1.z; a0.w += a1.w;
    a2.x += a3.x; a2.y += a3.y; a2.z += a3.z; a2.w += a3.w;
    a0.x += a2.x; a0.y += a2.y; a0.z += a2.z; a0.w += a2.w;

    __shared__ float4 red[4][64];
    red[g][lane] = a0;
    __syncthreads();

    if (g == 0) {
        float4 s0 = red[0][lane];
        float4 s1 = red[1][lane];
        float4 s2 = red[2][lane];
        float4 s3 = red[3][lane];
        float4 s;
        s.x = (s0.x + s1.x) + (s2.x + s3.x);
        s.y = (s0.y + s1.y) + (s2.y + s3.y);
        s.z = (s0.z + s1.z) + (s2.z + s3.z);
        s.w = (s0.w + s1.w) + (s2.w + s3.w);

        float4 p = *(reinterpret_cast<const float4*>(proto + (size_t)c * FEAT_DIM) + lane);
        float4 r = p;
        if (cnt > 0) {
            float inv = 1.0f / (float)cnt;
            r.x = MOMENTUM * p.x + (1.0f - MOMENTUM) * (s.x * inv);
            r.y = MOMENTUM * p.y + (1.0f - MOMENTUM) * (s.y * inv);
            r.z = MOMENTUM * p.z + (1.0f - MOMENTUM) * (s.z * inv);
            r.w = MOMENTUM * p.w + (1.0f - MOMENTUM) * (s.w * inv);
        }
        *(reinterpret_cast<float4*>(out + (size_t)c * FEAT_DIM) + lane) = r;
    }
}

// ---------------------------------------------------------------------------
extern "C" void kernel_launch(void* const* d_in, const int* in_sizes, int n_in,
                              void* d_out, int out_size, void* d_ws, size_t ws_size,
                              hipStream_t stream) {
    const float* feat   = (const float*)d_in[0];
    const int*   labels = (const int*)d_in[1];
    const float* proto  = (const float*)d_in[2];
    float*       out    = (float*)d_out;

    const int n = in_sizes[0] / FEAT_DIM;   // 262144
    // Defensive: if labels arrive as int64 reported as 2N int32 words, read
    // the little-endian low word with stride 2. Normally int32, stride 1.
    const int lstride = (in_sizes[1] >= 2 * n) ? 2 : 1;

    // Workspace layout (d_ws is re-poisoned 0xAA before every launch):
    char* ws = (char*)d_ws;
    int* counts  = (int*)(ws + 0);        // 1000 ints
    int* offsets = (int*)(ws + 4096);     // 1000 ints
    int* cursor  = (int*)(ws + 8192);     // 1000 ints
    int* idxbuf  = (int*)(ws + 12288);    // N ints (1 MB)

    hipMemsetAsync(counts, 0, NUM_CLASSES * sizeof(int), stream);

    hist_kernel<<<256, 256, 0, stream>>>(labels, lstride, n, counts);
    scan_kernel<<<1, 1024, 0, stream>>>(counts, offsets, cursor);
    scatter_kernel<<<256, 256, 0, stream>>>(labels, lstride, n, cursor, idxbuf);
    reduce_ema_kernel<<<NUM_CLASSES, FEAT_DIM, 0, stream>>>(
        feat, proto, offsets, counts, idxbuf, out);
}

// Round 6
// 396.120 us; speedup vs baseline: 1.0727x; 1.0727x over previous
//
#include <hip/hip_runtime.h>

#define NUM_CLASSES 1000
#define FEAT_DIM    256
#define MOMENTUM    0.9f
#define HB 64      // hist/scatter grid blocks (must match between the two)
#define HT 256     // hist/scatter block threads

// ---------------------------------------------------------------------------
// Kernel 1: per-block histogram. LDS-privatized (4 KB), then PLAIN stores of
// this block's histogram to counts_r[block][class]. No global atomics, no
// init required (every slot is overwritten).
// ---------------------------------------------------------------------------
__global__ void __launch_bounds__(HT) hist_kernel(
    const int* __restrict__ labels, int lstride, int n,
    int* __restrict__ counts_r) {
    __shared__ int h[NUM_CLASSES];
    for (int i = threadIdx.x; i < NUM_CLASSES; i += HT) h[i] = 0;
    __syncthreads();
    for (int i = blockIdx.x * HT + threadIdx.x; i < n; i += HB * HT)
        atomicAdd(&h[labels[(size_t)i * lstride]], 1);
    __syncthreads();
    for (int i = threadIdx.x; i < NUM_CLASSES; i += HT)
        counts_r[blockIdx.x * NUM_CLASSES + i] = h[i];
}

// ---------------------------------------------------------------------------
// Kernel 2: one block, thread t owns class t.
//  Phase A: serial exclusive prefix over the 64 block-histograms (coalesced:
//           for fixed b, threads read consecutive addresses).
//  Phase B: Hillis-Steele scan of per-class totals -> class bases.
//  Phase C: add class base to every per-block entry; emit offsets/counts.
// ---------------------------------------------------------------------------
__global__ void __launch_bounds__(1024) scan_kernel(
    int* __restrict__ counts_r, int* __restrict__ offsets,
    int* __restrict__ counts) {
    __shared__ int buf[1024];
    const int t = threadIdx.x;
    int run = 0;
    if (t < NUM_CLASSES) {
#pragma unroll 4
        for (int b = 0; b < HB; ++b) {
            int v = counts_r[b * NUM_CLASSES + t];
            counts_r[b * NUM_CLASSES + t] = run;   // intra-class block prefix
            run += v;
        }
    }
    buf[t] = (t < NUM_CLASSES) ? run : 0;
    __syncthreads();
    for (int off = 1; off < 1024; off <<= 1) {
        int x = (t >= off) ? buf[t - off] : 0;
        __syncthreads();
        buf[t] += x;
        __syncthreads();
    }
    if (t < NUM_CLASSES) {
        const int base = buf[t] - run;             // exclusive class base
        offsets[t] = base;
        counts[t]  = run;
#pragma unroll 4
        for (int b = 0; b < HB; ++b)
            counts_r[b * NUM_CLASSES + t] += base; // per-block absolute base
    }
}

// ---------------------------------------------------------------------------
// Kernel 3: deterministic scatter. Block b re-reads its rows (same mapping as
// hist), allocates positions from LDS cursors initialized to this block's
// absolute bases. Zero global atomics.
// ---------------------------------------------------------------------------
__global__ void __launch_bounds__(HT) scatter_kernel(
    const int* __restrict__ labels, int lstride, int n,
    const int* __restrict__ counts_r, int* __restrict__ idxbuf) {
    __shared__ int cur[NUM_CLASSES];
    for (int i = threadIdx.x; i < NUM_CLASSES; i += HT)
        cur[i] = counts_r[blockIdx.x * NUM_CLASSES + i];
    __syncthreads();
    for (int i = blockIdx.x * HT + threadIdx.x; i < n; i += HB * HT) {
        int c = labels[(size_t)i * lstride];
        int pos = atomicAdd(&cur[c], 1);
        idxbuf[pos] = i;
    }
}

// ---------------------------------------------------------------------------
// Kernel 4: per-class reduction + EMA. One block per class, 512 threads =
// 8 groups x 64 lanes (8000 waves total ~ full occupancy). Each group reads a
// whole 1 KB row as 64 x float4; groups stride the class row list by 8,
// unroll x4 => 4 outstanding 16 B loads/lane. LDS combine, EMA, float4 store.
// ---------------------------------------------------------------------------
__global__ void __launch_bounds__(512) reduce_ema_kernel(
    const float* __restrict__ feat, const float* __restrict__ proto,
    const int* __restrict__ offsets, const int* __restrict__ counts,
    const int* __restrict__ idxbuf, float* __restrict__ out) {
    const int c     = blockIdx.x;
    const int t     = threadIdx.x;
    const int g     = t >> 6;       // group 0..7
    const int lane  = t & 63;       // float4 slot within the row
    const int start = offsets[c];
    const int cnt   = counts[c];

    float4 a0 = make_float4(0.f, 0.f, 0.f, 0.f);
    float4 a1 = make_float4(0.f, 0.f, 0.f, 0.f);
    float4 a2 = make_float4(0.f, 0.f, 0.f, 0.f);
    float4 a3 = make_float4(0.f, 0.f, 0.f, 0.f);

    int j = g;
    for (; j + 24 < cnt; j += 32) {   // rows j, j+8, j+16, j+24 all valid
        int r0 = idxbuf[start + j];
        int r1 = idxbuf[start + j + 8];
        int r2 = idxbuf[start + j + 16];
        int r3 = idxbuf[start + j + 24];
        float4 f0 = *(reinterpret_cast<const float4*>(feat + (size_t)r0 * FEAT_DIM) + lane);
        float4 f1 = *(reinterpret_cast<const float4*>(feat + (size_t)r1 * FEAT_DIM) + lane);
        float4 f2 = *(reinterpret_cast<const float4*>(feat + (size_t)r2 * FEAT_DIM) + lane);
        float4 f3 = *(reinterpret_cast<const float4*>(feat + (size_t)r3 * FEAT_DIM) + lane);
        a0.x += f0.x; a0.y += f0.y; a0.z += f0.z; a0.w += f0.w;
        a1.x += f1.x; a1.y += f1.y; a1.z += f1.z; a1.w += f1.w;
        a2.x += f2.x; a2.y += f2.y; a2.z += f2.z; a2.w += f2.w;
        a3.x += f3.x; a3.y += f3.y; a3.z += f3.z; a3.w += f3.w;
    }
    for (; j < cnt; j += 8) {
        int r0 = idxbuf[start + j];
        float4 f0 = *(reinterpret_cast<const float4*>(feat + (size_t)r0 * FEAT_DIM) + lane);
        a0.x += f0.x; a0.y += f0.y; a0.z += f0.z; a0.w += f0.w;
    }
    a0.x += a1.x; a0.y += a1.y; a0.z += a1.z; a0.w += a1.w;
    a2.x += a3.x; a2.y += a3.y; a2.z += a3.z; a2.w += a3.w;
    a0.x += a2.x; a0.y += a2.y; a0.z += a2.z; a0.w += a2.w;

    __shared__ float4 red[8][64];
    red[g][lane] = a0;
    __syncthreads();

    if (g == 0) {
        float4 s = red[0][lane];
#pragma unroll
        for (int k = 1; k < 8; ++k) {
            float4 v = red[k][lane];
            s.x += v.x; s.y += v.y; s.z += v.z; s.w += v.w;
        }
        float4 p = *(reinterpret_cast<const float4*>(proto + (size_t)c * FEAT_DIM) + lane);
        float4 r = p;
        if (cnt > 0) {
            float inv = 1.0f / (float)cnt;
            r.x = MOMENTUM * p.x + (1.0f - MOMENTUM) * (s.x * inv);
            r.y = MOMENTUM * p.y + (1.0f - MOMENTUM) * (s.y * inv);
            r.z = MOMENTUM * p.z + (1.0f - MOMENTUM) * (s.z * inv);
            r.w = MOMENTUM * p.w + (1.0f - MOMENTUM) * (s.w * inv);
        }
        *(reinterpret_cast<float4*>(out + (size_t)c * FEAT_DIM) + lane) = r;
    }
}

// ---------------------------------------------------------------------------
extern "C" void kernel_launch(void* const* d_in, const int* in_sizes, int n_in,
                              void* d_out, int out_size, void* d_ws, size_t ws_size,
                              hipStream_t stream) {
    const float* feat   = (const float*)d_in[0];
    const int*   labels = (const int*)d_in[1];
    const float* proto  = (const float*)d_in[2];
    float*       out    = (float*)d_out;

    const int n = in_sizes[0] / FEAT_DIM;   // 262144
    // labels may be int64 surfaced as 2N int32 words (read LE low word,
    // stride 2) or plain int32 (stride 1).
    const int lstride = (in_sizes[1] >= 2 * n) ? 2 : 1;

    // Workspace layout (poisoned 0xAA each launch; everything fully
    // overwritten before being read):
    char* ws = (char*)d_ws;
    int* counts   = (int*)(ws + 0);                 // 1000 ints
    int* offsets  = (int*)(ws + 4096);              // 1000 ints
    int* counts_r = (int*)(ws + 8192);              // HB*1000 ints (256 KB)
    int* idxbuf   = (int*)(ws + 8192 + HB * NUM_CLASSES * sizeof(int) + 4096);

    hist_kernel<<<HB, HT, 0, stream>>>(labels, lstride, n, counts_r);
    scan_kernel<<<1, 1024, 0, stream>>>(counts_r, offsets, counts);
    scatter_kernel<<<HB, HT, 0, stream>>>(labels, lstride, n, counts_r, idxbuf);
    reduce_ema_kernel<<<NUM_CLASSES, 512, 0, stream>>>(
        feat, proto, offsets, counts, idxbuf, out);
}